// Round 1
// baseline (1376.972 us; speedup 1.0000x reference)
//
#include <hip/hip_runtime.h>
#include <math.h>

#define NN_   6000
#define EE_   192000
#define CIN_  32
#define CHID_ 64
#define KK_   125   // 5^3 spline kernel cells
#define SS_   8     // 2^3 corners

// ---------------------------------------------------------------------------
// Scatter: T[dst, idx, c] += basis * feat[src, c]   (fp32 atomics)
// One block per edge; thread = (s, c) with c innermost -> coalesced 128/256B
// atomic bursts per (e,s) unit. Also counts deg (x-pass only).
// ---------------------------------------------------------------------------
template<int CINT>
__global__ __launch_bounds__(8 * CINT) void scatter_kernel(
    const int* __restrict__ ei, const float* __restrict__ attr,
    const float* __restrict__ feat, float* __restrict__ T,
    float* __restrict__ deg)
{
    const int e   = blockIdx.x;
    const int tid = threadIdx.x;
    const int s   = tid / CINT;
    const int c   = tid % CINT;
    const int src = ei[e];
    const int dst = ei[EE_ + e];

    float f[3]; int i0[3];
#pragma unroll
    for (int d = 0; d < 3; ++d) {
        float u  = attr[e * 3 + d] * 4.0f;          // (KS-1) intervals
        float fl = floorf(u);
        fl = fminf(fmaxf(fl, 0.0f), 3.0f);          // clip to [0, KS-2]
        i0[d] = (int)fl;
        f[d]  = u - fl;                              // frac vs clipped i0 (ref)
    }
    const int b0 = s & 1, b1 = (s >> 1) & 1, b2 = (s >> 2) & 1;
    const int idx = (i0[0] + b0) * 25 + (i0[1] + b1) * 5 + (i0[2] + b2);
    const float basis = (b0 ? f[0] : 1.0f - f[0]) *
                        (b1 ? f[1] : 1.0f - f[1]) *
                        (b2 ? f[2] : 1.0f - f[2]);

    const float v = basis * feat[src * CINT + c];
    atomicAdd(&T[((size_t)dst * KK_ + idx) * CINT + c], v);

    if (deg != nullptr && tid == 0) atomicAdd(&deg[dst], 1.0f);
}

// ---------------------------------------------------------------------------
// Pack concatenated B matrices so one GEMM serves all convs of a family.
// B1 rows = (k*Cin + c), cols = conv*64 + o.
// ---------------------------------------------------------------------------
__global__ void pack_x_kernel(const float* __restrict__ Wa,
                              const float* __restrict__ Wb,
                              const float* __restrict__ Wc,
                              float* __restrict__ B1)
{
    int gid = blockIdx.x * 256 + threadIdx.x;
    if (gid >= KK_ * CIN_ * 192) return;
    int o    = gid & 63;
    int conv = (gid >> 6) % 3;
    int rc   = gid / 192;                     // k*Cin + c
    const float* W = (conv == 0) ? Wa : ((conv == 1) ? Wb : Wc);
    B1[gid] = W[rc * 64 + o];
}

__global__ void pack_h_kernel(const float* __restrict__ Wa,
                              const float* __restrict__ Wb,
                              float* __restrict__ B2)
{
    int gid = blockIdx.x * 256 + threadIdx.x;
    if (gid >= KK_ * CHID_ * 128) return;
    int o    = gid & 63;
    int conv = (gid >> 6) & 1;
    int rc   = gid >> 7;                      // k*Chid + c
    const float* W = (conv == 0) ? Wa : Wb;
    B2[gid] = W[rc * 64 + o];
}

// ---------------------------------------------------------------------------
// fp32 GEMM: C[M,Nn] = A[M,Kd] x B[Kd,Nn]. 64x64 tile, BK=16, 256 threads,
// 4x4 micro-tile/thread, As stored transposed for float4 LDS reads.
// ---------------------------------------------------------------------------
#define BM 64
#define BN 64
#define BK 16

__global__ __launch_bounds__(256) void gemm_kernel(
    const float* __restrict__ A, const float* __restrict__ B,
    float* __restrict__ C, int M, int Nn, int Kd)
{
    __shared__ float As[BK][BM];
    __shared__ float Bs[BK][BN];
    const int tid = threadIdx.x;
    const int tx = tid & 15, ty = tid >> 4;
    const int m0 = blockIdx.x * BM;
    const int n0 = blockIdx.y * BN;
    const int arow = tid >> 2;           // 0..63
    const int acol = (tid & 3) * 4;      // 0,4,8,12
    const int brow = tid >> 4;           // 0..15
    const int bcol = (tid & 15) * 4;     // 0..60

    float acc[4][4] = {};
    const int  am   = m0 + arow;
    const bool aval = am < M;
    const float* Aptr = A + (size_t)(aval ? am : 0) * Kd + acol;
    const float* Bptr = B + (size_t)brow * Nn + n0 + bcol;

    for (int k0 = 0; k0 < Kd; k0 += BK) {
        float4 a4 = aval ? *(const float4*)(Aptr + k0) : make_float4(0.f, 0.f, 0.f, 0.f);
        float4 b4 = *(const float4*)(Bptr + (size_t)k0 * Nn);
        As[acol + 0][arow] = a4.x;
        As[acol + 1][arow] = a4.y;
        As[acol + 2][arow] = a4.z;
        As[acol + 3][arow] = a4.w;
        *(float4*)&Bs[brow][bcol] = b4;
        __syncthreads();
#pragma unroll
        for (int kk = 0; kk < BK; ++kk) {
            float4 av = *(const float4*)&As[kk][ty * 4];
            float4 bv = *(const float4*)&Bs[kk][tx * 4];
            float a_[4] = {av.x, av.y, av.z, av.w};
            float b_[4] = {bv.x, bv.y, bv.z, bv.w};
#pragma unroll
            for (int i = 0; i < 4; ++i)
#pragma unroll
                for (int j = 0; j < 4; ++j)
                    acc[i][j] += a_[i] * b_[j];
        }
        __syncthreads();
    }

#pragma unroll
    for (int i = 0; i < 4; ++i) {
        int m = m0 + ty * 4 + i;
        if (m < M) {
#pragma unroll
            for (int j = 0; j < 4; ++j)
                C[(size_t)m * Nn + n0 + tx * 4 + j] = acc[i][j];
        }
    }
}

// ---------------------------------------------------------------------------
// Epilogue: mean-agg + root GEMV + bias + GRU gates, fused.
// 4 nodes / 256-thread block; thread = (node_sub, out_channel).
// ---------------------------------------------------------------------------
__global__ __launch_bounds__(256) void epilogue_kernel(
    const float* __restrict__ C1, const float* __restrict__ C2,
    const float* __restrict__ deg,
    const float* __restrict__ x, const float* __restrict__ hidden,
    const float* __restrict__ root_xr, const float* __restrict__ root_hr,
    const float* __restrict__ root_xz, const float* __restrict__ root_hz,
    const float* __restrict__ root_xn,
    const float* __restrict__ b_xr, const float* __restrict__ b_hr,
    const float* __restrict__ b_xz, const float* __restrict__ b_hz,
    const float* __restrict__ b_xn,
    float* __restrict__ out)
{
    const int node = blockIdx.x * 4 + (threadIdx.x >> 6);
    if (node >= NN_) return;
    const int o = threadIdx.x & 63;

    const float dinv = 1.0f / fmaxf(deg[node], 1.0f);
    const float axr = C1[(size_t)node * 192 + o]        * dinv;
    const float axz = C1[(size_t)node * 192 + 64 + o]   * dinv;
    const float axn = C1[(size_t)node * 192 + 128 + o]  * dinv;
    const float ahr = C2[(size_t)node * 128 + o]        * dinv;
    const float ahz = C2[(size_t)node * 128 + 64 + o]   * dinv;

    const float* xr_ = x + (size_t)node * CIN_;
    const float* hr_ = hidden + (size_t)node * CHID_;
    float sxr = 0.f, sxz = 0.f, sxn = 0.f;
#pragma unroll
    for (int c = 0; c < CIN_; ++c) {
        float xv = xr_[c];
        sxr += xv * root_xr[c * 64 + o];
        sxz += xv * root_xz[c * 64 + o];
        sxn += xv * root_xn[c * 64 + o];
    }
    float shr = 0.f, shz = 0.f;
#pragma unroll
    for (int c = 0; c < CHID_; ++c) {
        float hv = hr_[c];
        shr += hv * root_hr[c * 64 + o];
        shz += hv * root_hz[c * 64 + o];
    }

    const float conv_xr = axr + sxr + b_xr[o];
    const float conv_xz = axz + sxz + b_xz[o];
    const float conv_xn = axn + sxn + b_xn[o];
    const float hr_out  = ahr + shr + b_hr[o];
    const float conv_hz = ahz + shz + b_hz[o];

    const float r  = 1.0f / (1.0f + expf(-(conv_xr + hr_out)));
    const float z  = 1.0f / (1.0f + expf(-(conv_xz + conv_hz)));
    const float nn = tanhf(conv_xn + r * hr_out);
    out[(size_t)node * 64 + o] = (1.0f - z) * nn + z * hr_[o];
}

// ---------------------------------------------------------------------------
extern "C" void kernel_launch(void* const* d_in, const int* in_sizes, int n_in,
                              void* d_out, int out_size, void* d_ws, size_t ws_size,
                              hipStream_t stream)
{
    const float* x       = (const float*)d_in[0];
    const float* hidden  = (const float*)d_in[1];
    const int*   ei      = (const int*)  d_in[2];
    const float* attr    = (const float*)d_in[3];
    const float* W_xr    = (const float*)d_in[4];
    const float* root_xr = (const float*)d_in[5];
    const float* b_xr    = (const float*)d_in[6];
    const float* W_hr    = (const float*)d_in[7];
    const float* root_hr = (const float*)d_in[8];
    const float* b_hr    = (const float*)d_in[9];
    const float* W_xz    = (const float*)d_in[10];
    const float* root_xz = (const float*)d_in[11];
    const float* b_xz    = (const float*)d_in[12];
    const float* W_hz    = (const float*)d_in[13];
    const float* root_hz = (const float*)d_in[14];
    const float* b_hz    = (const float*)d_in[15];
    const float* W_xn    = (const float*)d_in[16];
    const float* root_xn = (const float*)d_in[17];
    const float* b_xn    = (const float*)d_in[18];
    // d_in[19..21] (W_hn/root_hn/b_hn) are dead: reference reuses hr_out.
    float* out = (float*)d_out;

    // Workspace layout (peak ~207 MB). T is reused: x-pass then h-pass.
    char* w = (char*)d_ws;
    float* T   = (float*)w;  w += (size_t)NN_ * KK_ * CHID_ * 4;  // 192 MB
    float* B1  = (float*)w;  w += (size_t)KK_ * CIN_  * 192 * 4;  // 3 MB
    float* B2  = (float*)w;  w += (size_t)KK_ * CHID_ * 128 * 4;  // 4 MB
    float* C1  = (float*)w;  w += (size_t)NN_ * 192 * 4;          // 4.6 MB
    float* C2  = (float*)w;  w += (size_t)NN_ * 128 * 4;          // 3 MB
    float* deg = (float*)w;  w += (size_t)NN_ * 4;

    // ---- x family: T_x -> C1 = T_x @ [W_xr | W_xz | W_xn] ----
    hipMemsetAsync(T, 0, (size_t)NN_ * KK_ * CIN_ * 4, stream);
    hipMemsetAsync(deg, 0, (size_t)NN_ * 4, stream);
    scatter_kernel<CIN_><<<EE_, 8 * CIN_, 0, stream>>>(ei, attr, x, T, deg);
    pack_x_kernel<<<(KK_ * CIN_ * 192 + 255) / 256, 256, 0, stream>>>(W_xr, W_xz, W_xn, B1);
    gemm_kernel<<<dim3((NN_ + BM - 1) / BM, 192 / BN), 256, 0, stream>>>(
        T, B1, C1, NN_, 192, KK_ * CIN_);

    // ---- h family: T_h -> C2 = T_h @ [W_hr | W_hz] ----
    hipMemsetAsync(T, 0, (size_t)NN_ * KK_ * CHID_ * 4, stream);
    scatter_kernel<CHID_><<<EE_, 8 * CHID_, 0, stream>>>(ei, attr, hidden, T, nullptr);
    pack_h_kernel<<<(KK_ * CHID_ * 128 + 255) / 256, 256, 0, stream>>>(W_hr, W_hz, B2);
    gemm_kernel<<<dim3((NN_ + BM - 1) / BM, 128 / BN), 256, 0, stream>>>(
        T, B2, C2, NN_, 128, KK_ * CHID_);

    // ---- fused GRU epilogue ----
    epilogue_kernel<<<(NN_ + 3) / 4, 256, 0, stream>>>(
        C1, C2, deg, x, hidden,
        root_xr, root_hr, root_xz, root_hz, root_xn,
        b_xr, b_hr, b_xz, b_hz, b_xn, out);
}

// Round 2
// 800.390 us; speedup vs baseline: 1.7204x; 1.7204x over previous
//
#include <hip/hip_runtime.h>
#include <math.h>

#define NN_   6000
#define EE_   192000
#define CIN_  32
#define CHID_ 64
#define KK_   125   // 5^3 spline kernel cells
#define SS_   8     // 2^3 corners

// fp32 -> bf16 round-to-nearest-even
static __device__ __forceinline__ unsigned short f2bf(float f) {
    unsigned int u = __builtin_bit_cast(unsigned int, f);
    u += 0x7fff + ((u >> 16) & 1);
    return (unsigned short)(u >> 16);
}

// ---------------------------------------------------------------------------
// Scatter: T[dst, idx, c] += basis * feat[src, c]   (fp32 atomics)
// One block per edge; thread = (s, c) with c innermost -> coalesced 128/256B
// atomic bursts per (e,s) unit. Also counts deg (x-pass only).
// ---------------------------------------------------------------------------
template<int CINT>
__global__ __launch_bounds__(8 * CINT) void scatter_kernel(
    const int* __restrict__ ei, const float* __restrict__ attr,
    const float* __restrict__ feat, float* __restrict__ T,
    float* __restrict__ deg)
{
    const int e   = blockIdx.x;
    const int tid = threadIdx.x;
    const int s   = tid / CINT;
    const int c   = tid % CINT;
    const int src = ei[e];
    const int dst = ei[EE_ + e];

    float f[3]; int i0[3];
#pragma unroll
    for (int d = 0; d < 3; ++d) {
        float u  = attr[e * 3 + d] * 4.0f;          // (KS-1) intervals
        float fl = floorf(u);
        fl = fminf(fmaxf(fl, 0.0f), 3.0f);          // clip to [0, KS-2]
        i0[d] = (int)fl;
        f[d]  = u - fl;
    }
    const int b0 = s & 1, b1 = (s >> 1) & 1, b2 = (s >> 2) & 1;
    const int idx = (i0[0] + b0) * 25 + (i0[1] + b1) * 5 + (i0[2] + b2);
    const float basis = (b0 ? f[0] : 1.0f - f[0]) *
                        (b1 ? f[1] : 1.0f - f[1]) *
                        (b2 ? f[2] : 1.0f - f[2]);

    const float v = basis * feat[src * CINT + c];
    atomicAdd(&T[((size_t)dst * KK_ + idx) * CINT + c], v);

    if (deg != nullptr && tid == 0) atomicAdd(&deg[dst], 1.0f);
}

// ---------------------------------------------------------------------------
// Pack weights into transposed bf16 B matrices: Bt[n][k], n = conv*64 + o,
// k = kcell*Cin + c. One GEMM then serves the whole conv family.
// ---------------------------------------------------------------------------
__global__ void pack_x_kernel(const float* __restrict__ Wa,
                              const float* __restrict__ Wb,
                              const float* __restrict__ Wc,
                              unsigned short* __restrict__ B1t)
{
    int gid = blockIdx.x * 256 + threadIdx.x;
    if (gid >= 192 * (KK_ * CIN_)) return;
    int n  = gid / (KK_ * CIN_);
    int kk = gid % (KK_ * CIN_);          // kcell*32 + c
    int conv = n >> 6, o = n & 63;
    const float* W = (conv == 0) ? Wa : ((conv == 1) ? Wb : Wc);
    B1t[gid] = f2bf(W[(size_t)kk * 64 + o]);
}

__global__ void pack_h_kernel(const float* __restrict__ Wa,
                              const float* __restrict__ Wb,
                              unsigned short* __restrict__ B2t)
{
    int gid = blockIdx.x * 256 + threadIdx.x;
    if (gid >= 128 * (KK_ * CHID_)) return;
    int n  = gid / (KK_ * CHID_);
    int kk = gid % (KK_ * CHID_);
    int conv = n >> 6, o = n & 63;
    const float* W = (conv == 0) ? Wa : Wb;
    B2t[gid] = f2bf(W[(size_t)kk * 64 + o]);
}

// ---------------------------------------------------------------------------
// MFMA bf16 GEMM with split-K: C[M,NT] += A[M,Kd] x Bt[NT,Kd]^T.
// A fp32 (converted to bf16 inline), Bt bf16 pre-transposed. 64-row tile x
// full NT, 4 waves (16 rows each), mfma_f32_16x16x32_bf16, fp32 atomicAdd
// into C. LDS rows padded to 40 shorts (80 B: 16B-aligned, bank stride 20
// words -> 2-way conflict = free).
// ---------------------------------------------------------------------------
template<int NT, int STEPS_PER_CHUNK>
__global__ __launch_bounds__(256) void mfma_gemm(
    const float* __restrict__ A, const unsigned short* __restrict__ Bt,
    float* __restrict__ C, int M, int Kd)
{
    constexpr int NFRAG = NT / 16;
    __shared__ unsigned short As[64][40];
    __shared__ unsigned short Bs[NT][40];

    using bf16x8 = __attribute__((ext_vector_type(8))) short;
    using f32x4  = __attribute__((ext_vector_type(4))) float;

    const int tid  = threadIdx.x;
    const int wave = tid >> 6;
    const int lane = tid & 63;
    const int quad = lane >> 4;
    const int l16  = lane & 15;
    const int m0   = blockIdx.x * 64;

    const int steps_total = Kd >> 5;
    const int s0 = blockIdx.y * STEPS_PER_CHUNK;
    const int s1 = min(steps_total, s0 + STEPS_PER_CHUNK);

    f32x4 acc[NFRAG];
#pragma unroll
    for (int f = 0; f < NFRAG; ++f) acc[f] = (f32x4){0.f, 0.f, 0.f, 0.f};

    // A loader: thread t -> row t>>2, 8 cols at (t&3)*8
    const int  arow   = tid >> 2;
    const int  acol   = (tid & 3) * 8;
    const bool avalid = (m0 + arow) < M;
    const float* Aptr = A + (size_t)(avalid ? (m0 + arow) : 0) * Kd + acol;

    for (int s = s0; s < s1; ++s) {
        const int k0 = s << 5;
        float4 a0 = make_float4(0.f, 0.f, 0.f, 0.f), a1 = a0;
        if (avalid) {
            a0 = *(const float4*)(Aptr + k0);
            a1 = *(const float4*)(Aptr + k0 + 4);
        }
        unsigned short t8[8] = {f2bf(a0.x), f2bf(a0.y), f2bf(a0.z), f2bf(a0.w),
                                f2bf(a1.x), f2bf(a1.y), f2bf(a1.z), f2bf(a1.w)};
        *(uint4*)&As[arow][acol] = *(uint4*)t8;

#pragma unroll
        for (int c = tid; c < NT * 4; c += 256) {
            int n = c >> 2, kc = (c & 3) * 8;
            *(uint4*)&Bs[n][kc] = *(const uint4*)(Bt + (size_t)n * Kd + k0 + kc);
        }
        __syncthreads();

        bf16x8 af = *(bf16x8*)&As[wave * 16 + l16][quad * 8];
#pragma unroll
        for (int f = 0; f < NFRAG; ++f) {
            bf16x8 bfv = *(bf16x8*)&Bs[f * 16 + l16][quad * 8];
            acc[f] = __builtin_amdgcn_mfma_f32_16x16x32_bf16(af, bfv, acc[f], 0, 0, 0);
        }
        __syncthreads();
    }

#pragma unroll
    for (int f = 0; f < NFRAG; ++f) {
#pragma unroll
        for (int r = 0; r < 4; ++r) {
            int m = m0 + wave * 16 + quad * 4 + r;
            if (m < M) atomicAdd(&C[(size_t)m * NT + f * 16 + l16], acc[f][r]);
        }
    }
}

// ---------------------------------------------------------------------------
// Epilogue: mean-agg + root GEMV + bias + GRU gates, fused.
// ---------------------------------------------------------------------------
__global__ __launch_bounds__(256) void epilogue_kernel(
    const float* __restrict__ C1, const float* __restrict__ C2,
    const float* __restrict__ deg,
    const float* __restrict__ x, const float* __restrict__ hidden,
    const float* __restrict__ root_xr, const float* __restrict__ root_hr,
    const float* __restrict__ root_xz, const float* __restrict__ root_hz,
    const float* __restrict__ root_xn,
    const float* __restrict__ b_xr, const float* __restrict__ b_hr,
    const float* __restrict__ b_xz, const float* __restrict__ b_hz,
    const float* __restrict__ b_xn,
    float* __restrict__ out)
{
    const int node = blockIdx.x * 4 + (threadIdx.x >> 6);
    if (node >= NN_) return;
    const int o = threadIdx.x & 63;

    const float dinv = 1.0f / fmaxf(deg[node], 1.0f);
    const float axr = C1[(size_t)node * 192 + o]        * dinv;
    const float axz = C1[(size_t)node * 192 + 64 + o]   * dinv;
    const float axn = C1[(size_t)node * 192 + 128 + o]  * dinv;
    const float ahr = C2[(size_t)node * 128 + o]        * dinv;
    const float ahz = C2[(size_t)node * 128 + 64 + o]   * dinv;

    const float* xr_ = x + (size_t)node * CIN_;
    const float* hr_ = hidden + (size_t)node * CHID_;
    float sxr = 0.f, sxz = 0.f, sxn = 0.f;
#pragma unroll
    for (int c = 0; c < CIN_; ++c) {
        float xv = xr_[c];
        sxr += xv * root_xr[c * 64 + o];
        sxz += xv * root_xz[c * 64 + o];
        sxn += xv * root_xn[c * 64 + o];
    }
    float shr = 0.f, shz = 0.f;
#pragma unroll
    for (int c = 0; c < CHID_; ++c) {
        float hv = hr_[c];
        shr += hv * root_hr[c * 64 + o];
        shz += hv * root_hz[c * 64 + o];
    }

    const float conv_xr = axr + sxr + b_xr[o];
    const float conv_xz = axz + sxz + b_xz[o];
    const float conv_xn = axn + sxn + b_xn[o];
    const float hr_out  = ahr + shr + b_hr[o];
    const float conv_hz = ahz + shz + b_hz[o];

    const float r  = 1.0f / (1.0f + expf(-(conv_xr + hr_out)));
    const float z  = 1.0f / (1.0f + expf(-(conv_xz + conv_hz)));
    const float nn = tanhf(conv_xn + r * hr_out);
    out[(size_t)node * 64 + o] = (1.0f - z) * nn + z * hr_[o];
}

// ---------------------------------------------------------------------------
extern "C" void kernel_launch(void* const* d_in, const int* in_sizes, int n_in,
                              void* d_out, int out_size, void* d_ws, size_t ws_size,
                              hipStream_t stream)
{
    const float* x       = (const float*)d_in[0];
    const float* hidden  = (const float*)d_in[1];
    const int*   ei      = (const int*)  d_in[2];
    const float* attr    = (const float*)d_in[3];
    const float* W_xr    = (const float*)d_in[4];
    const float* root_xr = (const float*)d_in[5];
    const float* b_xr    = (const float*)d_in[6];
    const float* W_hr    = (const float*)d_in[7];
    const float* root_hr = (const float*)d_in[8];
    const float* b_hr    = (const float*)d_in[9];
    const float* W_xz    = (const float*)d_in[10];
    const float* root_xz = (const float*)d_in[11];
    const float* b_xz    = (const float*)d_in[12];
    const float* W_hz    = (const float*)d_in[13];
    const float* root_hz = (const float*)d_in[14];
    const float* b_hz    = (const float*)d_in[15];
    const float* W_xn    = (const float*)d_in[16];
    const float* root_xn = (const float*)d_in[17];
    const float* b_xn    = (const float*)d_in[18];
    // d_in[19..21] (W_hn/root_hn/b_hn) are dead: reference reuses hr_out.
    float* out = (float*)d_out;

    // Workspace layout. T reused: x-pass then h-pass.
    char* w = (char*)d_ws;
    float* T             = (float*)w; w += (size_t)NN_ * KK_ * CHID_ * 4;  // 192 MB
    unsigned short* B1t  = (unsigned short*)w; w += (size_t)192 * KK_ * CIN_  * 2;
    unsigned short* B2t  = (unsigned short*)w; w += (size_t)128 * KK_ * CHID_ * 2;
    float* C1  = (float*)w; w += (size_t)NN_ * 192 * 4;
    float* C2  = (float*)w; w += (size_t)NN_ * 128 * 4;
    float* deg = (float*)w; w += (size_t)NN_ * 4;

    const int MT = (NN_ + 63) / 64;   // 94 m-tiles

    // ---- x family: T_x -> C1 = T_x @ [W_xr | W_xz | W_xn] ----
    hipMemsetAsync(T, 0, (size_t)NN_ * KK_ * CIN_ * 4, stream);
    hipMemsetAsync(deg, 0, (size_t)NN_ * 4, stream);
    hipMemsetAsync(C1, 0, (size_t)NN_ * 192 * 4, stream);
    hipMemsetAsync(C2, 0, (size_t)NN_ * 128 * 4, stream);
    scatter_kernel<CIN_><<<EE_, 8 * CIN_, 0, stream>>>(ei, attr, x, T, deg);
    pack_x_kernel<<<(192 * KK_ * CIN_ + 255) / 256, 256, 0, stream>>>(W_xr, W_xz, W_xn, B1t);
    {
        const int steps = (KK_ * CIN_) / 32;                 // 125
        const int chunks = (steps + 15) / 16;                // 8
        mfma_gemm<192, 16><<<dim3(MT, chunks), 256, 0, stream>>>(
            T, B1t, C1, NN_, KK_ * CIN_);
    }

    // ---- h family: T_h -> C2 = T_h @ [W_hr | W_hz] ----
    hipMemsetAsync(T, 0, (size_t)NN_ * KK_ * CHID_ * 4, stream);
    scatter_kernel<CHID_><<<EE_, 8 * CHID_, 0, stream>>>(ei, attr, hidden, T, nullptr);
    pack_h_kernel<<<(128 * KK_ * CHID_ + 255) / 256, 256, 0, stream>>>(W_hr, W_hz, B2t);
    {
        const int steps = (KK_ * CHID_) / 32;                // 250
        const int chunks = (steps + 15) / 16;                // 16
        mfma_gemm<128, 16><<<dim3(MT, chunks), 256, 0, stream>>>(
            T, B2t, C2, NN_, KK_ * CHID_);
    }

    // ---- fused GRU epilogue ----
    epilogue_kernel<<<(NN_ + 3) / 4, 256, 0, stream>>>(
        C1, C2, deg, x, hidden,
        root_xr, root_hr, root_xz, root_hz, root_xn,
        b_xr, b_hr, b_xz, b_hz, b_xn, out);
}